// Round 1
// baseline (990.082 us; speedup 1.0000x reference)
//
#include <hip/hip_runtime.h>

// ---------------- CSR construction ----------------

__global__ __launch_bounds__(256) void k_hist(const int* __restrict__ ei,
                                              int* __restrict__ cnt, int E) {
  int e = blockIdx.x * 256 + threadIdx.x;
  if (e < E) atomicAdd(&cnt[ei[E + e]], 1);
}

__global__ __launch_bounds__(1024) void k_scan(const int* __restrict__ cnt,
                                               int* __restrict__ rowptr,
                                               float* __restrict__ dinv,
                                               int N) {
  __shared__ int sums[1024];
  int t = threadIdx.x;
  int chunk = (N + 1023) >> 10;
  int lo = t * chunk;
  int hi = lo + chunk;
  if (lo > N) lo = N;
  if (hi > N) hi = N;
  int s = 0;
  for (int i = lo; i < hi; ++i) s += cnt[i];
  sums[t] = s;
  __syncthreads();
  // Hillis-Steele inclusive scan over 1024 partials
  for (int off = 1; off < 1024; off <<= 1) {
    int v = (t >= off) ? sums[t - off] : 0;
    __syncthreads();
    sums[t] += v;
    __syncthreads();
  }
  int run = sums[t] - s;  // exclusive prefix for this chunk
  for (int i = lo; i < hi; ++i) {
    int c = cnt[i];
    rowptr[i] = run;
    run += c;
    dinv[i] = rsqrtf((float)(c + 1));  // GCN degree includes self-loop
  }
  if (t == 1023) rowptr[N] = sums[1023];
}

__global__ __launch_bounds__(256) void k_fill(const int* __restrict__ ei,
                                              const int* __restrict__ rowptr,
                                              int* __restrict__ fill,
                                              int* __restrict__ col, int E) {
  int e = blockIdx.x * 256 + threadIdx.x;
  if (e < E) {
    int d = ei[E + e];
    int p = rowptr[d] + atomicAdd(&fill[d], 1);
    col[p] = ei[e];
  }
}

// ---------------- fp32 GEMM: C = A @ W^T  (A:[N,128], W:[128,128]) ----------------
// block = 256 threads, 32 rows/block, K staged in chunks of 32.
// thread (cg,rg) computes a 4x4 micro-tile: rows rg*4.., cols cg*4..

__global__ __launch_bounds__(256) void k_gemm1(const float* __restrict__ A,
                                               const float* __restrict__ W,
                                               float* __restrict__ C, int N) {
  __shared__ float Wt[32][132];  // Wt[k][o], padded pitch
  __shared__ float At[32][36];   // At[r][k], padded pitch
  int t = threadIdx.x;
  int r0 = blockIdx.x * 32;
  int cg = t & 31, rg = t >> 5;
  int c0 = cg * 4;
  float acc[4][4] = {};
  for (int kc = 0; kc < 128; kc += 32) {
    __syncthreads();
#pragma unroll
    for (int i = 0; i < 16; ++i) {
      int e = t + i * 256;
      int o = e >> 5, k = e & 31;
      Wt[k][o] = W[o * 128 + kc + k];
    }
    {
      int rr = t >> 3, c4 = (t & 7) * 4;
      int r = r0 + rr; if (r > N - 1) r = N - 1;
      *(float4*)&At[rr][c4] = *(const float4*)&A[(size_t)r * 128 + kc + c4];
    }
    __syncthreads();
#pragma unroll
    for (int k = 0; k < 32; k += 4) {
      float4 w0 = *(const float4*)&Wt[k + 0][c0];
      float4 w1 = *(const float4*)&Wt[k + 1][c0];
      float4 w2 = *(const float4*)&Wt[k + 2][c0];
      float4 w3 = *(const float4*)&Wt[k + 3][c0];
#pragma unroll
      for (int ri = 0; ri < 4; ++ri) {
        float4 a = *(const float4*)&At[rg * 4 + ri][k];
        acc[ri][0] += a.x * w0.x + a.y * w1.x + a.z * w2.x + a.w * w3.x;
        acc[ri][1] += a.x * w0.y + a.y * w1.y + a.z * w2.y + a.w * w3.y;
        acc[ri][2] += a.x * w0.z + a.y * w1.z + a.z * w2.z + a.w * w3.z;
        acc[ri][3] += a.x * w0.w + a.y * w1.w + a.z * w2.w + a.w * w3.w;
      }
    }
  }
#pragma unroll
  for (int ri = 0; ri < 4; ++ri) {
    int r = r0 + rg * 4 + ri;
    if (r < N) {
      float4 v = make_float4(acc[ri][0], acc[ri][1], acc[ri][2], acc[ri][3]);
      *(float4*)&C[(size_t)r * 128 + c0] = v;
    }
  }
}

// fused second-layer GEMM: out = relu(mean@Wl^T + x1@Wr^T + bl), in-place on x1
__global__ __launch_bounds__(256) void k_gemm2(const float* __restrict__ Amean,
                                               const float* __restrict__ Ax,
                                               const float* __restrict__ Wl,
                                               const float* __restrict__ Wr,
                                               const float* __restrict__ bl,
                                               float* __restrict__ out, int N) {
  __shared__ float Wt[32][132];
  __shared__ float At[32][36];
  int t = threadIdx.x;
  int r0 = blockIdx.x * 32;
  int cg = t & 31, rg = t >> 5;
  int c0 = cg * 4;
  float acc[4][4] = {};
  for (int ph = 0; ph < 2; ++ph) {
    const float* A = ph ? Ax : Amean;
    const float* W = ph ? Wr : Wl;
    for (int kc = 0; kc < 128; kc += 32) {
      __syncthreads();
#pragma unroll
      for (int i = 0; i < 16; ++i) {
        int e = t + i * 256;
        int o = e >> 5, k = e & 31;
        Wt[k][o] = W[o * 128 + kc + k];
      }
      {
        int rr = t >> 3, c4 = (t & 7) * 4;
        int r = r0 + rr; if (r > N - 1) r = N - 1;
        *(float4*)&At[rr][c4] = *(const float4*)&A[(size_t)r * 128 + kc + c4];
      }
      __syncthreads();
#pragma unroll
      for (int k = 0; k < 32; k += 4) {
        float4 w0 = *(const float4*)&Wt[k + 0][c0];
        float4 w1 = *(const float4*)&Wt[k + 1][c0];
        float4 w2 = *(const float4*)&Wt[k + 2][c0];
        float4 w3 = *(const float4*)&Wt[k + 3][c0];
#pragma unroll
        for (int ri = 0; ri < 4; ++ri) {
          float4 a = *(const float4*)&At[rg * 4 + ri][k];
          acc[ri][0] += a.x * w0.x + a.y * w1.x + a.z * w2.x + a.w * w3.x;
          acc[ri][1] += a.x * w0.y + a.y * w1.y + a.z * w2.y + a.w * w3.y;
          acc[ri][2] += a.x * w0.z + a.y * w1.z + a.z * w2.z + a.w * w3.z;
          acc[ri][3] += a.x * w0.w + a.y * w1.w + a.z * w2.w + a.w * w3.w;
        }
      }
    }
  }
  float4 b = *(const float4*)&bl[c0];
#pragma unroll
  for (int ri = 0; ri < 4; ++ri) {
    int r = r0 + rg * 4 + ri;
    if (r < N) {
      float4 v;
      v.x = fmaxf(acc[ri][0] + b.x, 0.f);
      v.y = fmaxf(acc[ri][1] + b.y, 0.f);
      v.z = fmaxf(acc[ri][2] + b.z, 0.f);
      v.w = fmaxf(acc[ri][3] + b.w, 0.f);
      *(float4*)&out[(size_t)r * 128 + c0] = v;
    }
  }
}

// ---------------- aggregations: one wave (64 lanes) per node, float2/lane ----------------

__global__ __launch_bounds__(256) void k_agg_gcn(const float* __restrict__ h,
                                                 const int* __restrict__ rowptr,
                                                 const int* __restrict__ col,
                                                 const float* __restrict__ dinv,
                                                 const float* __restrict__ b,
                                                 float* __restrict__ out, int N) {
  int wid = (blockIdx.x * 256 + threadIdx.x) >> 6;
  int lane = threadIdx.x & 63;
  if (wid >= N) return;
  const float2* h2 = (const float2*)h;
  float di = dinv[wid];
  float2 hv = h2[(size_t)wid * 64 + lane];
  float ax = hv.x * di, ay = hv.y * di;  // self-loop: h[i]*dinv[i] (x di again later)
  int s0 = rowptr[wid], s1 = rowptr[wid + 1];
  for (int j0 = s0; j0 < s1; j0 += 64) {
    int rem = s1 - j0;
    int idx = 0;
    float dv = 0.f;
    if (lane < rem) {
      idx = col[j0 + lane];
      dv = dinv[idx];
    }
    int m = rem < 64 ? rem : 64;
    for (int jj = 0; jj < m; ++jj) {
      int s = __shfl(idx, jj);
      float d = __shfl(dv, jj);
      float2 v = h2[(size_t)s * 64 + lane];
      ax += v.x * d;
      ay += v.y * d;
    }
  }
  float2 bb = ((const float2*)b)[lane];
  float ox = ax * di + bb.x;
  float oy = ay * di + bb.y;
  float2 res = make_float2(ox > 0.f ? ox : 0.f, oy > 0.f ? oy : 0.f);
  ((float2*)out)[(size_t)wid * 64 + lane] = res;
}

__global__ __launch_bounds__(256) void k_agg_mean(const float* __restrict__ x,
                                                  const int* __restrict__ rowptr,
                                                  const int* __restrict__ col,
                                                  float* __restrict__ meanout, int N) {
  int wid = (blockIdx.x * 256 + threadIdx.x) >> 6;
  int lane = threadIdx.x & 63;
  if (wid >= N) return;
  const float2* x2 = (const float2*)x;
  float ax = 0.f, ay = 0.f;
  int s0 = rowptr[wid], s1 = rowptr[wid + 1];
  for (int j0 = s0; j0 < s1; j0 += 64) {
    int rem = s1 - j0;
    int idx = 0;
    if (lane < rem) idx = col[j0 + lane];
    int m = rem < 64 ? rem : 64;
    for (int jj = 0; jj < m; ++jj) {
      int s = __shfl(idx, jj);
      float2 v = x2[(size_t)s * 64 + lane];
      ax += v.x;
      ay += v.y;
    }
  }
  int deg = s1 - s0;
  float inv = 1.f / (float)(deg > 0 ? deg : 1);
  ((float2*)meanout)[(size_t)wid * 64 + lane] = make_float2(ax * inv, ay * inv);
}

// ---------------- launch ----------------

extern "C" void kernel_launch(void* const* d_in, const int* in_sizes, int n_in,
                              void* d_out, int out_size, void* d_ws, size_t ws_size,
                              hipStream_t stream) {
  const float* feat = (const float*)d_in[0];
  const int* ei     = (const int*)d_in[1];
  const float* W1   = (const float*)d_in[2];
  const float* b1   = (const float*)d_in[3];
  const float* Wl   = (const float*)d_in[4];
  const float* bl   = (const float*)d_in[5];
  const float* Wr   = (const float*)d_in[6];
  float* out = (float*)d_out;

  int N = in_sizes[0] / 128;
  int E = in_sizes[1] / 2;

  char* ws = (char*)d_ws;
  size_t off = 0;
  auto alloc = [&](size_t bytes) {
    void* p = ws + off;
    off += (bytes + 255) & ~(size_t)255;
    return p;
  };
  float* h      = (float*)alloc((size_t)N * 128 * 4);  // reused as `mean` later
  int*   rowptr = (int*)alloc((size_t)(N + 1) * 4);
  int*   cnt    = (int*)alloc((size_t)N * 4);
  int*   fill   = (int*)alloc((size_t)N * 4);
  float* dinv   = (float*)alloc((size_t)N * 4);
  int*   col    = (int*)alloc((size_t)E * 4);

  hipMemsetAsync(cnt, 0, (size_t)N * 4, stream);
  hipMemsetAsync(fill, 0, (size_t)N * 4, stream);

  int eb = (E + 255) / 256;
  k_hist<<<eb, 256, 0, stream>>>(ei, cnt, E);
  k_scan<<<1, 1024, 0, stream>>>(cnt, rowptr, dinv, N);
  k_fill<<<eb, 256, 0, stream>>>(ei, rowptr, fill, col, E);

  // layer 1: h = feat @ W1^T ; x1 = relu(gcn_agg(h)) -> d_out
  k_gemm1<<<(N + 31) / 32, 256, 0, stream>>>(feat, W1, h, N);
  k_agg_gcn<<<(N + 3) / 4, 256, 0, stream>>>(h, rowptr, col, dinv, b1, out, N);

  // layer 2: mean agg of x1 -> h buffer; out = relu(mean@Wl^T + x1@Wr^T + bl)
  k_agg_mean<<<(N + 3) / 4, 256, 0, stream>>>(out, rowptr, col, h, N);
  k_gemm2<<<(N + 31) / 32, 256, 0, stream>>>(h, out, Wl, Wr, bl, out, N);
}

// Round 2
// 592.238 us; speedup vs baseline: 1.6718x; 1.6718x over previous
//
#include <hip/hip_runtime.h>

typedef unsigned int uint;
typedef unsigned short ushort;
typedef short sv8 __attribute__((ext_vector_type(8)));     // 8 bf16 (4 VGPR)
typedef float f32x4 __attribute__((ext_vector_type(4)));
typedef ushort u16x4 __attribute__((ext_vector_type(4)));
typedef ushort u16x8 __attribute__((ext_vector_type(8)));

__device__ __forceinline__ ushort f2b(float f) {  // fp32 -> bf16 RN
  uint u = __float_as_uint(f);
  return (ushort)((u + 0x7FFFu + ((u >> 16) & 1u)) >> 16);
}
__device__ __forceinline__ float b2f_lo(uint p) { return __uint_as_float(p << 16); }
__device__ __forceinline__ float b2f_hi(uint p) { return __uint_as_float(p & 0xFFFF0000u); }

#define MFMA16(acc, a, b) \
  asm volatile("v_mfma_f32_16x16x32_bf16 %0, %1, %2, %0" : "+v"(acc) : "v"(a), "v"(b))

// ---------------- CSR construction ----------------

__global__ __launch_bounds__(256) void k_hist(const int* __restrict__ ei,
                                              int* __restrict__ cnt, int E) {
  int e = blockIdx.x * 256 + threadIdx.x;
  if (e < E) atomicAdd(&cnt[ei[E + e]], 1);
}

__global__ __launch_bounds__(1024) void k_scan(const int* __restrict__ cnt,
                                               int* __restrict__ rowptr,
                                               float* __restrict__ dinv, int N) {
  __shared__ int sums[1024];
  int t = threadIdx.x;
  int chunk = (N + 1023) >> 10;
  int lo = t * chunk, hi = lo + chunk;
  if (lo > N) lo = N;
  if (hi > N) hi = N;
  int s = 0;
  for (int i = lo; i < hi; ++i) s += cnt[i];
  sums[t] = s;
  __syncthreads();
  for (int off = 1; off < 1024; off <<= 1) {
    int v = (t >= off) ? sums[t - off] : 0;
    __syncthreads();
    sums[t] += v;
    __syncthreads();
  }
  int run = sums[t] - s;
  for (int i = lo; i < hi; ++i) {
    int c = cnt[i];
    rowptr[i] = run;
    run += c;
    dinv[i] = rsqrtf((float)(c + 1));  // GCN degree includes self-loop
  }
  if (t == 1023) rowptr[N] = sums[1023];
}

__global__ __launch_bounds__(256) void k_fill(const int* __restrict__ ei,
                                              const int* __restrict__ rowptr,
                                              int* __restrict__ fill,
                                              int* __restrict__ col, int E) {
  int e = blockIdx.x * 256 + threadIdx.x;
  if (e < E) {
    int d = ei[E + e];
    int p = rowptr[d] + atomicAdd(&fill[d], 1);
    col[p] = ei[e];
  }
}

// ---------------- fp32 -> bf16 weight conversion ----------------

__global__ __launch_bounds__(256) void k_cvt(const float* __restrict__ src,
                                             ushort* __restrict__ dst, int n) {
  int i = blockIdx.x * 256 + threadIdx.x;
  if (i < n) dst[i] = f2b(src[i]);
}

// ---------------- GEMM1: Hb(bf16) = feat(fp32) @ W1^T (MFMA bf16) ----------------
// block = 256 thr = 4 waves; 128 rows/block (32/wave); K=128 in 4 k-tiles.
// W in LDS [128][128] bf16, 16B slots XOR-swizzled by (row&7) -> 2-way max.

__global__ __launch_bounds__(256) void k_gemm1(const float* __restrict__ A,
                                               const ushort* __restrict__ Wb,
                                               ushort* __restrict__ Hb, int N) {
  __shared__ __align__(16) ushort smem[17408];  // 34816 B: W tile 32KB, epilogue 4x[32][136]
  int t = threadIdx.x;
#pragma unroll
  for (int i = 0; i < 8; ++i) {
    int c = t + i * 256;
    int row = c >> 4, slot = c & 15;
    *(u16x8*)&smem[row * 128 + ((slot ^ (row & 7)) << 3)] =
        *(const u16x8*)&Wb[row * 128 + (slot << 3)];
  }
  __syncthreads();

  int wv = t >> 6, l = t & 63;
  int lr = l & 15, lk = l >> 4;
  int r0 = blockIdx.x * 128 + wv * 32;
  f32x4 acc[2][8];
#pragma unroll
  for (int rb = 0; rb < 2; ++rb)
#pragma unroll
    for (int ct = 0; ct < 8; ++ct) acc[rb][ct] = (f32x4){0.f, 0.f, 0.f, 0.f};

#pragma unroll
  for (int kk = 0; kk < 4; ++kk) {
    sv8 af[2];
#pragma unroll
    for (int rb = 0; rb < 2; ++rb) {
      int r = r0 + rb * 16 + lr;
      if (r >= N) r = N - 1;
      const float* ap = &A[(size_t)r * 128 + kk * 32 + lk * 8];
      float4 a0 = *(const float4*)ap;
      float4 a1 = *(const float4*)(ap + 4);
      af[rb] = (sv8){(short)f2b(a0.x), (short)f2b(a0.y), (short)f2b(a0.z), (short)f2b(a0.w),
                     (short)f2b(a1.x), (short)f2b(a1.y), (short)f2b(a1.z), (short)f2b(a1.w)};
    }
#pragma unroll
    for (int ct = 0; ct < 8; ++ct) {
      int brow = ct * 16 + lr;
      sv8 bf = *(const sv8*)&smem[brow * 128 + (((kk * 4 + lk) ^ (brow & 7)) << 3)];
      MFMA16(acc[0][ct], af[0], bf);
      MFMA16(acc[1][ct], af[1], bf);
    }
  }
  asm volatile("s_nop 7\n\ts_nop 7");  // MFMA->VALU read hazard margin (inline-asm mfma)
  __syncthreads();
  // epilogue: repack C tile via per-wave LDS for coalesced bf16 stores
  ushort* ep = smem + wv * (32 * 136);
#pragma unroll
  for (int rb = 0; rb < 2; ++rb)
#pragma unroll
    for (int ct = 0; ct < 8; ++ct)
#pragma unroll
      for (int i = 0; i < 4; ++i)
        ep[(rb * 16 + lk * 4 + i) * 136 + ct * 16 + lr] = f2b(acc[rb][ct][i]);
#pragma unroll
  for (int it = 0; it < 4; ++it) {
    int row = it * 8 + (l >> 3);
    int gr = r0 + row;
    if (gr < N) {
#pragma unroll
      for (int cc = 0; cc < 2; ++cc) {
        int colv = cc * 64 + (l & 7) * 8;
        *(u16x8*)&Hb[(size_t)gr * 128 + colv] = *(const u16x8*)&ep[row * 136 + colv];
      }
    }
  }
}

// ---------------- GEMM2: Out(fp32) = relu(mean@Wl^T + x1@Wr^T + bl) ----------------

__global__ __launch_bounds__(256) void k_gemm2(const ushort* __restrict__ Mb,
                                               const ushort* __restrict__ X1b,
                                               const ushort* __restrict__ Wlb,
                                               const ushort* __restrict__ Wrb,
                                               const float* __restrict__ bl,
                                               float* __restrict__ Out, int N) {
  __shared__ __align__(16) ushort smem[2 * 128 * 128];  // 65536 B; epilogue reuses 33792 B
  int t = threadIdx.x;
#pragma unroll
  for (int i = 0; i < 8; ++i) {
    int c = t + i * 256;
    int row = c >> 4, slot = c & 15;
    int off = (slot ^ (row & 7)) << 3;
    *(u16x8*)&smem[row * 128 + off] = *(const u16x8*)&Wlb[row * 128 + (slot << 3)];
    *(u16x8*)&smem[16384 + row * 128 + off] = *(const u16x8*)&Wrb[row * 128 + (slot << 3)];
  }
  __syncthreads();

  int wv = t >> 6, l = t & 63;
  int lr = l & 15, lk = l >> 4;
  int r0 = blockIdx.x * 128 + wv * 32;
  f32x4 acc[2][8];
#pragma unroll
  for (int rb = 0; rb < 2; ++rb)
#pragma unroll
    for (int ct = 0; ct < 8; ++ct) acc[rb][ct] = (f32x4){0.f, 0.f, 0.f, 0.f};

#pragma unroll
  for (int ph = 0; ph < 2; ++ph) {
    const ushort* Ab = ph ? X1b : Mb;
    const ushort* Wp = smem + ph * 16384;
#pragma unroll
    for (int kk = 0; kk < 4; ++kk) {
      sv8 af[2];
#pragma unroll
      for (int rb = 0; rb < 2; ++rb) {
        int r = r0 + rb * 16 + lr;
        if (r >= N) r = N - 1;
        af[rb] = *(const sv8*)&Ab[(size_t)r * 128 + kk * 32 + lk * 8];
      }
#pragma unroll
      for (int ct = 0; ct < 8; ++ct) {
        int brow = ct * 16 + lr;
        sv8 bf = *(const sv8*)&Wp[brow * 128 + (((kk * 4 + lk) ^ (brow & 7)) << 3)];
        MFMA16(acc[0][ct], af[0], bf);
        MFMA16(acc[1][ct], af[1], bf);
      }
    }
  }
  asm volatile("s_nop 7\n\ts_nop 7");
  __syncthreads();
  float* epf = (float*)smem + wv * (16 * 132);  // per-wave fp32 staging [16][132]
#pragma unroll
  for (int rb = 0; rb < 2; ++rb) {
#pragma unroll
    for (int ct = 0; ct < 8; ++ct) {
      float bb = bl[ct * 16 + lr];
#pragma unroll
      for (int i = 0; i < 4; ++i)
        epf[(lk * 4 + i) * 132 + ct * 16 + lr] = fmaxf(acc[rb][ct][i] + bb, 0.f);
    }
#pragma unroll
    for (int it = 0; it < 2; ++it) {
      int row = it * 8 + (l >> 3);
      int gr = r0 + rb * 16 + row;
      if (gr < N) {
#pragma unroll
        for (int cc = 0; cc < 4; ++cc) {
          int colv = cc * 32 + (l & 7) * 4;
          *(float4*)&Out[(size_t)gr * 128 + colv] = *(const float4*)&epf[row * 132 + colv];
        }
      }
    }
  }
}

// ---------------- aggregations: wave per node, 2 neighbor rows per iter ----------------

__global__ __launch_bounds__(256) void k_agg_gcn(const ushort* __restrict__ Hb,
                                                 const int* __restrict__ rowptr,
                                                 const int* __restrict__ col,
                                                 const float* __restrict__ dinv,
                                                 const float* __restrict__ bias,
                                                 ushort* __restrict__ X1b, int N) {
  int wid = (blockIdx.x * 256 + threadIdx.x) >> 6;
  int l = threadIdx.x & 63;
  if (wid >= N) return;
  int lc = l & 31, half = l >> 5;
  float di = dinv[wid];
  float a0 = 0.f, a1 = 0.f, a2 = 0.f, a3 = 0.f;
  int s0 = rowptr[wid], s1 = rowptr[wid + 1];
  for (int j0 = s0; j0 < s1; j0 += 64) {
    int rem = s1 - j0;
    int idx = 0;
    float dv = 0.f;
    if (l < rem) {
      idx = col[j0 + l];
      dv = dinv[idx];
    }
    int m = rem < 64 ? rem : 64;
    for (int jj = 0; jj < m; jj += 2) {
      int js = jj + half;
      int s = __shfl(idx, js);
      float d = __shfl(dv, js);  // lanes past rem carry dv=0,idx=0 -> no contribution
      uint2 v = *(const uint2*)&Hb[(size_t)s * 128 + lc * 4];
      a0 = fmaf(b2f_lo(v.x), d, a0);
      a1 = fmaf(b2f_hi(v.x), d, a1);
      a2 = fmaf(b2f_lo(v.y), d, a2);
      a3 = fmaf(b2f_hi(v.y), d, a3);
    }
  }
  a0 += __shfl_xor(a0, 32);
  a1 += __shfl_xor(a1, 32);
  a2 += __shfl_xor(a2, 32);
  a3 += __shfl_xor(a3, 32);
  if (half == 0) {
    uint2 hv = *(const uint2*)&Hb[(size_t)wid * 128 + lc * 4];
    float4 bb = *(const float4*)&bias[lc * 4];
    float o0 = (a0 + b2f_lo(hv.x) * di) * di + bb.x;
    float o1 = (a1 + b2f_hi(hv.x) * di) * di + bb.y;
    float o2 = (a2 + b2f_lo(hv.y) * di) * di + bb.z;
    float o3 = (a3 + b2f_hi(hv.y) * di) * di + bb.w;
    u16x4 r = {f2b(fmaxf(o0, 0.f)), f2b(fmaxf(o1, 0.f)),
               f2b(fmaxf(o2, 0.f)), f2b(fmaxf(o3, 0.f))};
    *(u16x4*)&X1b[(size_t)wid * 128 + lc * 4] = r;
  }
}

__global__ __launch_bounds__(256) void k_agg_mean(const ushort* __restrict__ Xb,
                                                  const int* __restrict__ rowptr,
                                                  const int* __restrict__ col,
                                                  ushort* __restrict__ Mb, int N) {
  int wid = (blockIdx.x * 256 + threadIdx.x) >> 6;
  int l = threadIdx.x & 63;
  if (wid >= N) return;
  int lc = l & 31, half = l >> 5;
  float a0 = 0.f, a1 = 0.f, a2 = 0.f, a3 = 0.f;
  int s0 = rowptr[wid], s1 = rowptr[wid + 1];
  for (int j0 = s0; j0 < s1; j0 += 64) {
    int rem = s1 - j0;
    int idx = 0;
    float w = 0.f;
    if (l < rem) {
      idx = col[j0 + l];
      w = 1.f;
    }
    int m = rem < 64 ? rem : 64;
    for (int jj = 0; jj < m; jj += 2) {
      int js = jj + half;
      int s = __shfl(idx, js);
      float d = __shfl(w, js);
      uint2 v = *(const uint2*)&Xb[(size_t)s * 128 + lc * 4];
      a0 = fmaf(b2f_lo(v.x), d, a0);
      a1 = fmaf(b2f_hi(v.x), d, a1);
      a2 = fmaf(b2f_lo(v.y), d, a2);
      a3 = fmaf(b2f_hi(v.y), d, a3);
    }
  }
  a0 += __shfl_xor(a0, 32);
  a1 += __shfl_xor(a1, 32);
  a2 += __shfl_xor(a2, 32);
  a3 += __shfl_xor(a3, 32);
  if (half == 0) {
    int deg = s1 - s0;
    float inv = 1.f / (float)(deg > 0 ? deg : 1);
    u16x4 r = {f2b(a0 * inv), f2b(a1 * inv), f2b(a2 * inv), f2b(a3 * inv)};
    *(u16x4*)&Mb[(size_t)wid * 128 + lc * 4] = r;
  }
}

// ---------------- launch ----------------

extern "C" void kernel_launch(void* const* d_in, const int* in_sizes, int n_in,
                              void* d_out, int out_size, void* d_ws, size_t ws_size,
                              hipStream_t stream) {
  const float* feat = (const float*)d_in[0];
  const int* ei     = (const int*)d_in[1];
  const float* W1   = (const float*)d_in[2];
  const float* b1   = (const float*)d_in[3];
  const float* Wl   = (const float*)d_in[4];
  const float* bl   = (const float*)d_in[5];
  const float* Wr   = (const float*)d_in[6];
  float* out = (float*)d_out;

  int N = in_sizes[0] / 128;
  int E = in_sizes[1] / 2;

  char* ws = (char*)d_ws;
  size_t off = 0;
  auto alloc = [&](size_t bytes) {
    void* p = ws + off;
    off += (bytes + 255) & ~(size_t)255;
    return p;
  };
  ushort* Hb    = (ushort*)alloc((size_t)N * 128 * 2);  // h bf16; reused as mean
  ushort* X1b   = (ushort*)alloc((size_t)N * 128 * 2);  // layer-1 output bf16
  int*   rowptr = (int*)alloc((size_t)(N + 1) * 4);
  int*   cnt    = (int*)alloc((size_t)N * 4);
  int*   fill   = (int*)alloc((size_t)N * 4);
  float* dinv   = (float*)alloc((size_t)N * 4);
  int*   col    = (int*)alloc((size_t)E * 4);
  ushort* W1b   = (ushort*)alloc(16384 * 2);
  ushort* Wlb   = (ushort*)alloc(16384 * 2);
  ushort* Wrb   = (ushort*)alloc(16384 * 2);

  hipMemsetAsync(cnt, 0, (size_t)N * 4, stream);
  hipMemsetAsync(fill, 0, (size_t)N * 4, stream);

  int eb = (E + 255) / 256;
  k_hist<<<eb, 256, 0, stream>>>(ei, cnt, E);
  k_scan<<<1, 1024, 0, stream>>>(cnt, rowptr, dinv, N);
  k_fill<<<eb, 256, 0, stream>>>(ei, rowptr, fill, col, E);

  k_cvt<<<64, 256, 0, stream>>>(W1, W1b, 16384);
  k_cvt<<<64, 256, 0, stream>>>(Wl, Wlb, 16384);
  k_cvt<<<64, 256, 0, stream>>>(Wr, Wrb, 16384);

  int gb = (N + 127) / 128;
  k_gemm1<<<gb, 256, 0, stream>>>(feat, W1b, Hb, N);
  k_agg_gcn<<<(N + 3) / 4, 256, 0, stream>>>(Hb, rowptr, col, dinv, b1, X1b, N);
  k_agg_mean<<<(N + 3) / 4, 256, 0, stream>>>(X1b, rowptr, col, Hb, N);
  k_gemm2<<<gb, 256, 0, stream>>>(Hb, X1b, Wlb, Wrb, bl, out, N);
}

// Round 3
// 340.792 us; speedup vs baseline: 2.9052x; 1.7378x over previous
//
#include <hip/hip_runtime.h>

typedef unsigned int uint;
typedef unsigned short ushort;
typedef short sv8 __attribute__((ext_vector_type(8)));     // 8 bf16 (4 VGPR)
typedef float f32x4 __attribute__((ext_vector_type(4)));
typedef ushort u16x4 __attribute__((ext_vector_type(4)));
typedef ushort u16x8 __attribute__((ext_vector_type(8)));

__device__ __forceinline__ ushort f2b(float f) {  // fp32 -> bf16 RN
  uint u = __float_as_uint(f);
  return (ushort)((u + 0x7FFFu + ((u >> 16) & 1u)) >> 16);
}
__device__ __forceinline__ float b2f_lo(uint p) { return __uint_as_float(p << 16); }
__device__ __forceinline__ float b2f_hi(uint p) { return __uint_as_float(p & 0xFFFF0000u); }

#define MFMA16(acc, a, b) \
  asm volatile("v_mfma_f32_16x16x32_bf16 %0, %1, %2, %0" : "+v"(acc) : "v"(a), "v"(b))

// ---------------- CSR construction ----------------

__global__ __launch_bounds__(256) void k_hist(const int* __restrict__ ei,
                                              int* __restrict__ cnt, int E) {
  int e = blockIdx.x * 256 + threadIdx.x;
  if (e < E) atomicAdd(&cnt[ei[E + e]], 1);
}

// block-local exclusive scan: 2048 elements/block, coalesced int4 loads
__global__ __launch_bounds__(256) void k_scan_blk(const int* __restrict__ cnt,
                                                  int* __restrict__ rowptr,
                                                  float* __restrict__ dinv,
                                                  int* __restrict__ blksum, int N) {
  __shared__ int sums[256];
  int t = threadIdx.x;
  int base = blockIdx.x * 2048 + t * 8;
  int loc[8] = {0, 0, 0, 0, 0, 0, 0, 0};
  if (base + 8 <= N) {
    int4 c0 = *(const int4*)&cnt[base];
    int4 c1 = *(const int4*)&cnt[base + 4];
    loc[0] = c0.x; loc[1] = c0.y; loc[2] = c0.z; loc[3] = c0.w;
    loc[4] = c1.x; loc[5] = c1.y; loc[6] = c1.z; loc[7] = c1.w;
  } else if (base < N) {
#pragma unroll
    for (int k = 0; k < 8; ++k)
      if (base + k < N) loc[k] = cnt[base + k];
  }
  int pre[8], s = 0;
#pragma unroll
  for (int k = 0; k < 8; ++k) { pre[k] = s; s += loc[k]; }
  sums[t] = s;
  __syncthreads();
  for (int off = 1; off < 256; off <<= 1) {
    int v = (t >= off) ? sums[t - off] : 0;
    __syncthreads();
    sums[t] += v;
    __syncthreads();
  }
  int texcl = sums[t] - s;
#pragma unroll
  for (int k = 0; k < 8; ++k) {
    if (base + k < N) {
      rowptr[base + k] = texcl + pre[k];
      dinv[base + k] = rsqrtf((float)(loc[k] + 1));  // GCN degree incl self-loop
    }
  }
  if (t == 255) blksum[blockIdx.x] = sums[255];
}

__global__ __launch_bounds__(1024) void k_scan_top(const int* __restrict__ blksum,
                                                   int* __restrict__ blkoff,
                                                   int* __restrict__ rowptr,
                                                   int NB, int N) {
  __shared__ int s[1024];
  int t = threadIdx.x;
  int v = (t < NB) ? blksum[t] : 0;
  s[t] = v;
  __syncthreads();
  for (int off = 1; off < 1024; off <<= 1) {
    int u = (t >= off) ? s[t - off] : 0;
    __syncthreads();
    s[t] += u;
    __syncthreads();
  }
  if (t < NB) blkoff[t] = s[t] - v;
  if (t == 1023) rowptr[N] = s[1023];
}

__global__ __launch_bounds__(256) void k_scan_add(int* __restrict__ rowptr,
                                                  const int* __restrict__ blkoff, int N) {
  int i = blockIdx.x * 256 + threadIdx.x;
  if (i < N) rowptr[i] += blkoff[i >> 11];
}

__global__ __launch_bounds__(256) void k_fill(const int* __restrict__ ei,
                                              const int* __restrict__ rowptr,
                                              int* __restrict__ fill,
                                              int* __restrict__ col, int E) {
  int e = blockIdx.x * 256 + threadIdx.x;
  if (e < E) {
    int d = ei[E + e];
    int p = rowptr[d] + atomicAdd(&fill[d], 1);
    col[p] = ei[e];
  }
}

// ---------------- fp32 -> bf16 weight conversion (all 3 weights, one launch) ----------

__global__ __launch_bounds__(256) void k_cvt3(const float* __restrict__ s0,
                                              const float* __restrict__ s1,
                                              const float* __restrict__ s2,
                                              ushort* __restrict__ d0,
                                              ushort* __restrict__ d1,
                                              ushort* __restrict__ d2) {
  int i = blockIdx.x * 256 + threadIdx.x;
  if (i < 16384) {
    d0[i] = f2b(s0[i]);
    d1[i] = f2b(s1[i]);
    d2[i] = f2b(s2[i]);
  }
}

// ---------------- GEMM1: Hb(bf16) = feat(fp32) @ W1^T (MFMA bf16) ----------------

__global__ __launch_bounds__(256) void k_gemm1(const float* __restrict__ A,
                                               const ushort* __restrict__ Wb,
                                               ushort* __restrict__ Hb, int N) {
  __shared__ __align__(16) ushort smem[17408];  // W tile 32KB; epilogue 4x[32][136]
  int t = threadIdx.x;
#pragma unroll
  for (int i = 0; i < 8; ++i) {
    int c = t + i * 256;
    int row = c >> 4, slot = c & 15;
    *(u16x8*)&smem[row * 128 + ((slot ^ (row & 7)) << 3)] =
        *(const u16x8*)&Wb[row * 128 + (slot << 3)];
  }
  __syncthreads();

  int wv = t >> 6, l = t & 63;
  int lr = l & 15, lk = l >> 4;
  int r0 = blockIdx.x * 128 + wv * 32;
  f32x4 acc[2][8];
#pragma unroll
  for (int rb = 0; rb < 2; ++rb)
#pragma unroll
    for (int ct = 0; ct < 8; ++ct) acc[rb][ct] = (f32x4){0.f, 0.f, 0.f, 0.f};

#pragma unroll
  for (int kk = 0; kk < 4; ++kk) {
    sv8 af[2];
#pragma unroll
    for (int rb = 0; rb < 2; ++rb) {
      int r = r0 + rb * 16 + lr;
      if (r >= N) r = N - 1;
      const float* ap = &A[(size_t)r * 128 + kk * 32 + lk * 8];
      float4 a0 = *(const float4*)ap;
      float4 a1 = *(const float4*)(ap + 4);
      af[rb] = (sv8){(short)f2b(a0.x), (short)f2b(a0.y), (short)f2b(a0.z), (short)f2b(a0.w),
                     (short)f2b(a1.x), (short)f2b(a1.y), (short)f2b(a1.z), (short)f2b(a1.w)};
    }
#pragma unroll
    for (int ct = 0; ct < 8; ++ct) {
      int brow = ct * 16 + lr;
      sv8 bf = *(const sv8*)&smem[brow * 128 + (((kk * 4 + lk) ^ (brow & 7)) << 3)];
      MFMA16(acc[0][ct], af[0], bf);
      MFMA16(acc[1][ct], af[1], bf);
    }
  }
  asm volatile("s_nop 7\n\ts_nop 7");
  __syncthreads();
  ushort* ep = smem + wv * (32 * 136);
#pragma unroll
  for (int rb = 0; rb < 2; ++rb)
#pragma unroll
    for (int ct = 0; ct < 8; ++ct)
#pragma unroll
      for (int i = 0; i < 4; ++i)
        ep[(rb * 16 + lk * 4 + i) * 136 + ct * 16 + lr] = f2b(acc[rb][ct][i]);
#pragma unroll
  for (int it = 0; it < 4; ++it) {
    int row = it * 8 + (l >> 3);
    int gr = r0 + row;
    if (gr < N) {
#pragma unroll
      for (int cc = 0; cc < 2; ++cc) {
        int colv = cc * 64 + (l & 7) * 8;
        *(u16x8*)&Hb[(size_t)gr * 128 + colv] = *(const u16x8*)&ep[row * 136 + colv];
      }
    }
  }
}

// ---------------- GEMM2: Out(fp32) = relu(mean@Wl^T + x1@Wr^T + bl) ----------------

__global__ __launch_bounds__(256) void k_gemm2(const ushort* __restrict__ Mb,
                                               const ushort* __restrict__ X1b,
                                               const ushort* __restrict__ Wlb,
                                               const ushort* __restrict__ Wrb,
                                               const float* __restrict__ bl,
                                               float* __restrict__ Out, int N) {
  __shared__ __align__(16) ushort smem[2 * 128 * 128];
  int t = threadIdx.x;
#pragma unroll
  for (int i = 0; i < 8; ++i) {
    int c = t + i * 256;
    int row = c >> 4, slot = c & 15;
    int off = (slot ^ (row & 7)) << 3;
    *(u16x8*)&smem[row * 128 + off] = *(const u16x8*)&Wlb[row * 128 + (slot << 3)];
    *(u16x8*)&smem[16384 + row * 128 + off] = *(const u16x8*)&Wrb[row * 128 + (slot << 3)];
  }
  __syncthreads();

  int wv = t >> 6, l = t & 63;
  int lr = l & 15, lk = l >> 4;
  int r0 = blockIdx.x * 128 + wv * 32;
  f32x4 acc[2][8];
#pragma unroll
  for (int rb = 0; rb < 2; ++rb)
#pragma unroll
    for (int ct = 0; ct < 8; ++ct) acc[rb][ct] = (f32x4){0.f, 0.f, 0.f, 0.f};

#pragma unroll
  for (int ph = 0; ph < 2; ++ph) {
    const ushort* Ab = ph ? X1b : Mb;
    const ushort* Wp = smem + ph * 16384;
#pragma unroll
    for (int kk = 0; kk < 4; ++kk) {
      sv8 af[2];
#pragma unroll
      for (int rb = 0; rb < 2; ++rb) {
        int r = r0 + rb * 16 + lr;
        if (r >= N) r = N - 1;
        af[rb] = *(const sv8*)&Ab[(size_t)r * 128 + kk * 32 + lk * 8];
      }
#pragma unroll
      for (int ct = 0; ct < 8; ++ct) {
        int brow = ct * 16 + lr;
        sv8 bf = *(const sv8*)&Wp[brow * 128 + (((kk * 4 + lk) ^ (brow & 7)) << 3)];
        MFMA16(acc[0][ct], af[0], bf);
        MFMA16(acc[1][ct], af[1], bf);
      }
    }
  }
  asm volatile("s_nop 7\n\ts_nop 7");
  __syncthreads();
  float* epf = (float*)smem + wv * (16 * 132);
#pragma unroll
  for (int rb = 0; rb < 2; ++rb) {
#pragma unroll
    for (int ct = 0; ct < 8; ++ct) {
      float bb = bl[ct * 16 + lr];
#pragma unroll
      for (int i = 0; i < 4; ++i)
        epf[(lk * 4 + i) * 132 + ct * 16 + lr] = fmaxf(acc[rb][ct][i] + bb, 0.f);
    }
#pragma unroll
    for (int it = 0; it < 2; ++it) {
      int row = it * 8 + (l >> 3);
      int gr = r0 + rb * 16 + row;
      if (gr < N) {
#pragma unroll
        for (int cc = 0; cc < 4; ++cc) {
          int colv = cc * 32 + (l & 7) * 4;
          *(float4*)&Out[(size_t)gr * 128 + colv] = *(const float4*)&epf[row * 132 + colv];
        }
      }
    }
  }
}

// ---------------- aggregations: wave/node, 16-lane x uint4 rows, 8 rows in flight ----

__global__ __launch_bounds__(256) void k_agg_gcn(const ushort* __restrict__ Hb,
                                                 const int* __restrict__ rowptr,
                                                 const int* __restrict__ col,
                                                 const float* __restrict__ dinv,
                                                 const float* __restrict__ bias,
                                                 ushort* __restrict__ X1b, int N) {
  int wid = (blockIdx.x * 256 + threadIdx.x) >> 6;
  int l = threadIdx.x & 63;
  if (wid >= N) return;
  int q = l >> 4, lc = l & 15;
  float di = dinv[wid];
  float acc[8] = {0.f, 0.f, 0.f, 0.f, 0.f, 0.f, 0.f, 0.f};
  int s0 = rowptr[wid], s1 = rowptr[wid + 1];
  for (int j0 = s0; j0 < s1; j0 += 64) {
    int rem = s1 - j0;
    int idx = 0;
    float dv = 0.f;
    if (l < rem) {
      idx = col[j0 + l];
      dv = dinv[idx];
    }
    int m = rem < 64 ? rem : 64;
    for (int jj = 0; jj < m; jj += 8) {
      int ra = jj + q, rb = jj + 4 + q;
      int sa = __shfl(idx, ra); float da = __shfl(dv, ra);
      int sb = __shfl(idx, rb); float db = __shfl(dv, rb);  // rows >= rem carry d=0
      uint4 va = *(const uint4*)&Hb[(size_t)sa * 128 + lc * 8];
      uint4 vb = *(const uint4*)&Hb[(size_t)sb * 128 + lc * 8];
      acc[0] = fmaf(b2f_lo(va.x), da, acc[0]); acc[1] = fmaf(b2f_hi(va.x), da, acc[1]);
      acc[2] = fmaf(b2f_lo(va.y), da, acc[2]); acc[3] = fmaf(b2f_hi(va.y), da, acc[3]);
      acc[4] = fmaf(b2f_lo(va.z), da, acc[4]); acc[5] = fmaf(b2f_hi(va.z), da, acc[5]);
      acc[6] = fmaf(b2f_lo(va.w), da, acc[6]); acc[7] = fmaf(b2f_hi(va.w), da, acc[7]);
      acc[0] = fmaf(b2f_lo(vb.x), db, acc[0]); acc[1] = fmaf(b2f_hi(vb.x), db, acc[1]);
      acc[2] = fmaf(b2f_lo(vb.y), db, acc[2]); acc[3] = fmaf(b2f_hi(vb.y), db, acc[3]);
      acc[4] = fmaf(b2f_lo(vb.z), db, acc[4]); acc[5] = fmaf(b2f_hi(vb.z), db, acc[5]);
      acc[6] = fmaf(b2f_lo(vb.w), db, acc[6]); acc[7] = fmaf(b2f_hi(vb.w), db, acc[7]);
    }
  }
#pragma unroll
  for (int k = 0; k < 8; ++k) {
    acc[k] += __shfl_xor(acc[k], 16);
    acc[k] += __shfl_xor(acc[k], 32);
  }
  if (q == 0) {
    uint4 hv = *(const uint4*)&Hb[(size_t)wid * 128 + lc * 8];
    float4 b0 = *(const float4*)&bias[lc * 8];
    float4 b1 = *(const float4*)&bias[lc * 8 + 4];
    float hvf[8] = {b2f_lo(hv.x), b2f_hi(hv.x), b2f_lo(hv.y), b2f_hi(hv.y),
                    b2f_lo(hv.z), b2f_hi(hv.z), b2f_lo(hv.w), b2f_hi(hv.w)};
    float bb[8] = {b0.x, b0.y, b0.z, b0.w, b1.x, b1.y, b1.z, b1.w};
    u16x8 r;
#pragma unroll
    for (int k = 0; k < 8; ++k) {
      float o = (acc[k] + hvf[k] * di) * di + bb[k];
      r[k] = f2b(fmaxf(o, 0.f));
    }
    *(u16x8*)&X1b[(size_t)wid * 128 + lc * 8] = r;
  }
}

__global__ __launch_bounds__(256) void k_agg_mean(const ushort* __restrict__ Xb,
                                                  const int* __restrict__ rowptr,
                                                  const int* __restrict__ col,
                                                  ushort* __restrict__ Mb, int N) {
  int wid = (blockIdx.x * 256 + threadIdx.x) >> 6;
  int l = threadIdx.x & 63;
  if (wid >= N) return;
  int q = l >> 4, lc = l & 15;
  float acc[8] = {0.f, 0.f, 0.f, 0.f, 0.f, 0.f, 0.f, 0.f};
  int s0 = rowptr[wid], s1 = rowptr[wid + 1];
  for (int j0 = s0; j0 < s1; j0 += 64) {
    int rem = s1 - j0;
    int idx = 0;
    float w = 0.f;
    if (l < rem) {
      idx = col[j0 + l];
      w = 1.f;
    }
    int m = rem < 64 ? rem : 64;
    for (int jj = 0; jj < m; jj += 8) {
      int ra = jj + q, rb = jj + 4 + q;
      int sa = __shfl(idx, ra); float da = __shfl(w, ra);
      int sb = __shfl(idx, rb); float db = __shfl(w, rb);
      uint4 va = *(const uint4*)&Xb[(size_t)sa * 128 + lc * 8];
      uint4 vb = *(const uint4*)&Xb[(size_t)sb * 128 + lc * 8];
      acc[0] = fmaf(b2f_lo(va.x), da, acc[0]); acc[1] = fmaf(b2f_hi(va.x), da, acc[1]);
      acc[2] = fmaf(b2f_lo(va.y), da, acc[2]); acc[3] = fmaf(b2f_hi(va.y), da, acc[3]);
      acc[4] = fmaf(b2f_lo(va.z), da, acc[4]); acc[5] = fmaf(b2f_hi(va.z), da, acc[5]);
      acc[6] = fmaf(b2f_lo(va.w), da, acc[6]); acc[7] = fmaf(b2f_hi(va.w), da, acc[7]);
      acc[0] = fmaf(b2f_lo(vb.x), db, acc[0]); acc[1] = fmaf(b2f_hi(vb.x), db, acc[1]);
      acc[2] = fmaf(b2f_lo(vb.y), db, acc[2]); acc[3] = fmaf(b2f_hi(vb.y), db, acc[3]);
      acc[4] = fmaf(b2f_lo(vb.z), db, acc[4]); acc[5] = fmaf(b2f_hi(vb.z), db, acc[5]);
      acc[6] = fmaf(b2f_lo(vb.w), db, acc[6]); acc[7] = fmaf(b2f_hi(vb.w), db, acc[7]);
    }
  }
#pragma unroll
  for (int k = 0; k < 8; ++k) {
    acc[k] += __shfl_xor(acc[k], 16);
    acc[k] += __shfl_xor(acc[k], 32);
  }
  if (q == 0) {
    int deg = s1 - s0;
    float inv = 1.f / (float)(deg > 0 ? deg : 1);
    u16x8 r;
#pragma unroll
    for (int k = 0; k < 8; ++k) r[k] = f2b(acc[k] * inv);
    *(u16x8*)&Mb[(size_t)wid * 128 + lc * 8] = r;
  }
}

// ---------------- launch ----------------

extern "C" void kernel_launch(void* const* d_in, const int* in_sizes, int n_in,
                              void* d_out, int out_size, void* d_ws, size_t ws_size,
                              hipStream_t stream) {
  const float* feat = (const float*)d_in[0];
  const int* ei     = (const int*)d_in[1];
  const float* W1   = (const float*)d_in[2];
  const float* b1   = (const float*)d_in[3];
  const float* Wl   = (const float*)d_in[4];
  const float* bl   = (const float*)d_in[5];
  const float* Wr   = (const float*)d_in[6];
  float* out = (float*)d_out;

  int N = in_sizes[0] / 128;
  int E = in_sizes[1] / 2;

  char* ws = (char*)d_ws;
  size_t off = 0;
  auto alloc = [&](size_t bytes) {
    void* p = ws + off;
    off += (bytes + 255) & ~(size_t)255;
    return p;
  };
  ushort* Hb    = (ushort*)alloc((size_t)N * 128 * 2);  // h bf16; reused as mean
  ushort* X1b   = (ushort*)alloc((size_t)N * 128 * 2);  // layer-1 output bf16
  int*   rowptr = (int*)alloc((size_t)(N + 1) * 4);
  int*   cnt    = (int*)alloc((size_t)N * 4);
  int*   fill   = (int*)alloc((size_t)N * 4);
  float* dinv   = (float*)alloc((size_t)N * 4);
  int*   col    = (int*)alloc((size_t)E * 4);
  int*   blksum = (int*)alloc(1024 * 4);
  int*   blkoff = (int*)alloc(1024 * 4);
  ushort* W1b   = (ushort*)alloc(16384 * 2);
  ushort* Wlb   = (ushort*)alloc(16384 * 2);
  ushort* Wrb   = (ushort*)alloc(16384 * 2);

  hipMemsetAsync(cnt, 0, (size_t)N * 4, stream);
  hipMemsetAsync(fill, 0, (size_t)N * 4, stream);

  int eb = (E + 255) / 256;
  int NB = (N + 2047) / 2048;
  k_hist<<<eb, 256, 0, stream>>>(ei, cnt, E);
  k_scan_blk<<<NB, 256, 0, stream>>>(cnt, rowptr, dinv, blksum, N);
  k_scan_top<<<1, 1024, 0, stream>>>(blksum, blkoff, rowptr, NB, N);
  k_scan_add<<<(N + 255) / 256, 256, 0, stream>>>(rowptr, blkoff, N);
  k_fill<<<eb, 256, 0, stream>>>(ei, rowptr, fill, col, E);

  k_cvt3<<<64, 256, 0, stream>>>(W1, Wl, Wr, W1b, Wlb, Wrb);

  int gb = (N + 127) / 128;
  k_gemm1<<<gb, 256, 0, stream>>>(feat, W1b, Hb, N);
  k_agg_gcn<<<(N + 3) / 4, 256, 0, stream>>>(Hb, rowptr, col, dinv, b1, X1b, N);
  k_agg_mean<<<(N + 3) / 4, 256, 0, stream>>>(X1b, rowptr, col, Hb, N);
  k_gemm2<<<gb, 256, 0, stream>>>(Hb, X1b, Wlb, Wrb, bl, out, N);
}

// Round 4
// 221.420 us; speedup vs baseline: 4.4715x; 1.5391x over previous
//
#include <hip/hip_runtime.h>

typedef unsigned int uint;
typedef unsigned short ushort;
typedef short sv8 __attribute__((ext_vector_type(8)));     // 8 bf16 (4 VGPR)
typedef float f32x4 __attribute__((ext_vector_type(4)));
typedef ushort u16x4 __attribute__((ext_vector_type(4)));
typedef ushort u16x8 __attribute__((ext_vector_type(8)));

__device__ __forceinline__ ushort f2b(float f) {  // fp32 -> bf16 RN
  uint u = __float_as_uint(f);
  return (ushort)((u + 0x7FFFu + ((u >> 16) & 1u)) >> 16);
}
__device__ __forceinline__ float b2f_lo(uint p) { return __uint_as_float(p << 16); }
__device__ __forceinline__ float b2f_hi(uint p) { return __uint_as_float(p & 0xFFFF0000u); }

#define MFMA16(acc, a, b) \
  asm volatile("v_mfma_f32_16x16x32_bf16 %0, %1, %2, %0" : "+v"(acc) : "v"(a), "v"(b))

// ================= bucketed CSR build =================
// bucket = dst >> 10 (1024 nodes/bucket). NB <= 256 supported.
// chunk per block = 16384 edges.

__global__ __launch_bounds__(256) void k_bhist(const int* __restrict__ dst,
                                               int* __restrict__ bhist, int E) {
  __shared__ int h[256];
  int t = threadIdx.x;
  h[t] = 0;
  __syncthreads();
#pragma unroll
  for (int i = 0; i < 16; ++i) {
    int idx = blockIdx.x * 16384 + i * 1024 + t * 4;
    if (idx + 4 <= E) {
      int4 d = *(const int4*)&dst[idx];
      atomicAdd(&h[d.x >> 10], 1);
      atomicAdd(&h[d.y >> 10], 1);
      atomicAdd(&h[d.z >> 10], 1);
      atomicAdd(&h[d.w >> 10], 1);
    } else {
      for (int k = 0; k < 4; ++k)
        if (idx + k < E) atomicAdd(&h[dst[idx + k] >> 10], 1);
    }
  }
  __syncthreads();
  if (h[t] > 0) atomicAdd(&bhist[t], h[t]);
}

__global__ __launch_bounds__(256) void k_bscan(const int* __restrict__ bhist,
                                               int* __restrict__ bbase,
                                               int* __restrict__ bcursor,
                                               int* __restrict__ rowptr,
                                               int NB, int N, int E) {
  __shared__ int s[256];
  int t = threadIdx.x;
  int v = (t < NB) ? bhist[t] : 0;
  s[t] = v;
  __syncthreads();
  for (int off = 1; off < 256; off <<= 1) {
    int u = (t >= off) ? s[t - off] : 0;
    __syncthreads();
    s[t] += u;
    __syncthreads();
  }
  if (t < NB) {
    bbase[t] = s[t] - v;
    bcursor[t] = s[t] - v;
  }
  if (t == 0) rowptr[N] = E;
}

__global__ __launch_bounds__(256) void k_scatter(const int* __restrict__ ei,
                                                 int* __restrict__ bcursor,
                                                 uint2* __restrict__ keyval, int E) {
  __shared__ int h[256];
  __shared__ int base[256];
  int t = threadIdx.x;
  h[t] = 0;
  __syncthreads();
  // pass 1: local bucket histogram
#pragma unroll
  for (int i = 0; i < 16; ++i) {
    int idx = blockIdx.x * 16384 + i * 1024 + t * 4;
    if (idx + 4 <= E) {
      int4 d = *(const int4*)&ei[E + idx];
      atomicAdd(&h[d.x >> 10], 1);
      atomicAdd(&h[d.y >> 10], 1);
      atomicAdd(&h[d.z >> 10], 1);
      atomicAdd(&h[d.w >> 10], 1);
    } else {
      for (int k = 0; k < 4; ++k)
        if (idx + k < E) atomicAdd(&h[ei[E + idx + k] >> 10], 1);
    }
  }
  __syncthreads();
  // reserve contiguous per-bucket ranges for this block
  int hv = h[t];
  base[t] = (hv > 0) ? atomicAdd(&bcursor[t], hv) : 0;
  __syncthreads();
  h[t] = 0;
  __syncthreads();
  // pass 2: scatter (src,dst) pairs into bucket-grouped order
#pragma unroll
  for (int i = 0; i < 16; ++i) {
    int idx = blockIdx.x * 16384 + i * 1024 + t * 4;
    if (idx + 4 <= E) {
      int4 sv = *(const int4*)&ei[idx];
      int4 dv = *(const int4*)&ei[E + idx];
      int b0 = dv.x >> 10, b1 = dv.y >> 10, b2 = dv.z >> 10, b3 = dv.w >> 10;
      int r0 = atomicAdd(&h[b0], 1);
      keyval[base[b0] + r0] = make_uint2((uint)sv.x, (uint)dv.x);
      int r1 = atomicAdd(&h[b1], 1);
      keyval[base[b1] + r1] = make_uint2((uint)sv.y, (uint)dv.y);
      int r2 = atomicAdd(&h[b2], 1);
      keyval[base[b2] + r2] = make_uint2((uint)sv.z, (uint)dv.z);
      int r3 = atomicAdd(&h[b3], 1);
      keyval[base[b3] + r3] = make_uint2((uint)sv.w, (uint)dv.w);
    } else {
      for (int k = 0; k < 4; ++k)
        if (idx + k < E) {
          int sv = ei[idx + k], dv = ei[E + idx + k];
          int b = dv >> 10;
          int r = atomicAdd(&h[b], 1);
          keyval[base[b] + r] = make_uint2((uint)sv, (uint)dv);
        }
    }
  }
}

// one block per bucket: per-node counts, local scan, rowptr/dinv, col scatter
__global__ __launch_bounds__(1024) void k_build(const uint2* __restrict__ keyval,
                                                const int* __restrict__ bbase,
                                                const int* __restrict__ bhist,
                                                int* __restrict__ rowptr,
                                                float* __restrict__ dinv,
                                                int* __restrict__ col, int N) {
  __shared__ int c[1024];
  int b = blockIdx.x, t = threadIdx.x;
  int ebase = bbase[b], ecnt = bhist[b];
  int node0 = b << 10;
  c[t] = 0;
  __syncthreads();
  for (int i = t; i < ecnt; i += 1024)
    atomicAdd(&c[keyval[ebase + i].y - node0], 1);
  __syncthreads();
  int v = c[t];
  for (int off = 1; off < 1024; off <<= 1) {
    int u = (t >= off) ? c[t - off] : 0;
    __syncthreads();
    c[t] += u;
    __syncthreads();
  }
  int excl = c[t] - v;
  int node = node0 + t;
  if (node < N) {
    rowptr[node] = ebase + excl;
    dinv[node] = rsqrtf((float)(v + 1));  // GCN degree incl self-loop
  }
  __syncthreads();
  c[t] = excl;
  __syncthreads();
  for (int i = t; i < ecnt; i += 1024) {
    uint2 kv = keyval[ebase + i];
    int r = atomicAdd(&c[kv.y - node0], 1);
    col[ebase + r] = (int)kv.x;
  }
}

// ================= GEMM1: Hb(bf16) = feat(fp32) @ W1^T =================

__global__ __launch_bounds__(256) void k_gemm1(const float* __restrict__ A,
                                               const float* __restrict__ W,
                                               ushort* __restrict__ Hb, int N) {
  __shared__ __align__(16) ushort smem[17408];  // W tile 32KB; epilogue 4x[32][136]
  int t = threadIdx.x;
#pragma unroll
  for (int i = 0; i < 8; ++i) {
    int c_ = t + i * 256;
    int row = c_ >> 4, slot = c_ & 15;
    const float* wp = &W[row * 128 + slot * 8];
    float4 w0 = *(const float4*)wp;
    float4 w1 = *(const float4*)(wp + 4);
    u16x8 v = {f2b(w0.x), f2b(w0.y), f2b(w0.z), f2b(w0.w),
               f2b(w1.x), f2b(w1.y), f2b(w1.z), f2b(w1.w)};
    *(u16x8*)&smem[row * 128 + ((slot ^ (row & 7)) << 3)] = v;
  }
  __syncthreads();

  int wv = t >> 6, l = t & 63;
  int lr = l & 15, lk = l >> 4;
  int r0 = blockIdx.x * 128 + wv * 32;
  f32x4 acc[2][8];
#pragma unroll
  for (int rb = 0; rb < 2; ++rb)
#pragma unroll
    for (int ct = 0; ct < 8; ++ct) acc[rb][ct] = (f32x4){0.f, 0.f, 0.f, 0.f};

#pragma unroll
  for (int kk = 0; kk < 4; ++kk) {
    sv8 af[2];
#pragma unroll
    for (int rb = 0; rb < 2; ++rb) {
      int r = r0 + rb * 16 + lr;
      if (r >= N) r = N - 1;
      const float* ap = &A[(size_t)r * 128 + kk * 32 + lk * 8];
      float4 a0 = *(const float4*)ap;
      float4 a1 = *(const float4*)(ap + 4);
      af[rb] = (sv8){(short)f2b(a0.x), (short)f2b(a0.y), (short)f2b(a0.z), (short)f2b(a0.w),
                     (short)f2b(a1.x), (short)f2b(a1.y), (short)f2b(a1.z), (short)f2b(a1.w)};
    }
#pragma unroll
    for (int ct = 0; ct < 8; ++ct) {
      int brow = ct * 16 + lr;
      sv8 bf = *(const sv8*)&smem[brow * 128 + (((kk * 4 + lk) ^ (brow & 7)) << 3)];
      MFMA16(acc[0][ct], af[0], bf);
      MFMA16(acc[1][ct], af[1], bf);
    }
  }
  asm volatile("s_nop 7\n\ts_nop 7");
  __syncthreads();
  ushort* ep = smem + wv * (32 * 136);
#pragma unroll
  for (int rb = 0; rb < 2; ++rb)
#pragma unroll
    for (int ct = 0; ct < 8; ++ct)
#pragma unroll
      for (int i = 0; i < 4; ++i)
        ep[(rb * 16 + lk * 4 + i) * 136 + ct * 16 + lr] = f2b(acc[rb][ct][i]);
#pragma unroll
  for (int it = 0; it < 4; ++it) {
    int row = it * 8 + (l >> 3);
    int gr = r0 + row;
    if (gr < N) {
#pragma unroll
      for (int cc = 0; cc < 2; ++cc) {
        int colv = cc * 64 + (l & 7) * 8;
        *(u16x8*)&Hb[(size_t)gr * 128 + colv] = *(const u16x8*)&ep[row * 136 + colv];
      }
    }
  }
}

// ================= GEMM2: Out = relu(mean@Wl^T + x1@Wr^T + bl) =================

__global__ __launch_bounds__(256) void k_gemm2(const ushort* __restrict__ Mb,
                                               const ushort* __restrict__ X1b,
                                               const float* __restrict__ Wl,
                                               const float* __restrict__ Wr,
                                               const float* __restrict__ bl,
                                               float* __restrict__ Out, int N) {
  __shared__ __align__(16) ushort smem[2 * 128 * 128];
  int t = threadIdx.x;
#pragma unroll
  for (int i = 0; i < 8; ++i) {
    int c_ = t + i * 256;
    int row = c_ >> 4, slot = c_ & 15;
    int off = (slot ^ (row & 7)) << 3;
    {
      const float* wp = &Wl[row * 128 + slot * 8];
      float4 w0 = *(const float4*)wp;
      float4 w1 = *(const float4*)(wp + 4);
      u16x8 v = {f2b(w0.x), f2b(w0.y), f2b(w0.z), f2b(w0.w),
                 f2b(w1.x), f2b(w1.y), f2b(w1.z), f2b(w1.w)};
      *(u16x8*)&smem[row * 128 + off] = v;
    }
    {
      const float* wp = &Wr[row * 128 + slot * 8];
      float4 w0 = *(const float4*)wp;
      float4 w1 = *(const float4*)(wp + 4);
      u16x8 v = {f2b(w0.x), f2b(w0.y), f2b(w0.z), f2b(w0.w),
                 f2b(w1.x), f2b(w1.y), f2b(w1.z), f2b(w1.w)};
      *(u16x8*)&smem[16384 + row * 128 + off] = v;
    }
  }
  __syncthreads();

  int wv = t >> 6, l = t & 63;
  int lr = l & 15, lk = l >> 4;
  int r0 = blockIdx.x * 128 + wv * 32;
  f32x4 acc[2][8];
#pragma unroll
  for (int rb = 0; rb < 2; ++rb)
#pragma unroll
    for (int ct = 0; ct < 8; ++ct) acc[rb][ct] = (f32x4){0.f, 0.f, 0.f, 0.f};

#pragma unroll
  for (int ph = 0; ph < 2; ++ph) {
    const ushort* Ab = ph ? X1b : Mb;
    const ushort* Wp = smem + ph * 16384;
#pragma unroll
    for (int kk = 0; kk < 4; ++kk) {
      sv8 af[2];
#pragma unroll
      for (int rb = 0; rb < 2; ++rb) {
        int r = r0 + rb * 16 + lr;
        if (r >= N) r = N - 1;
        af[rb] = *(const sv8*)&Ab[(size_t)r * 128 + kk * 32 + lk * 8];
      }
#pragma unroll
      for (int ct = 0; ct < 8; ++ct) {
        int brow = ct * 16 + lr;
        sv8 bf = *(const sv8*)&Wp[brow * 128 + (((kk * 4 + lk) ^ (brow & 7)) << 3)];
        MFMA16(acc[0][ct], af[0], bf);
        MFMA16(acc[1][ct], af[1], bf);
      }
    }
  }
  asm volatile("s_nop 7\n\ts_nop 7");
  __syncthreads();
  float* epf = (float*)smem + wv * (16 * 132);
#pragma unroll
  for (int rb = 0; rb < 2; ++rb) {
#pragma unroll
    for (int ct = 0; ct < 8; ++ct) {
      float bb = bl[ct * 16 + lr];
#pragma unroll
      for (int i = 0; i < 4; ++i)
        epf[(lk * 4 + i) * 132 + ct * 16 + lr] = fmaxf(acc[rb][ct][i] + bb, 0.f);
    }
#pragma unroll
    for (int it = 0; it < 2; ++it) {
      int row = it * 8 + (l >> 3);
      int gr = r0 + rb * 16 + row;
      if (gr < N) {
#pragma unroll
        for (int cc = 0; cc < 4; ++cc) {
          int colv = cc * 32 + (l & 7) * 4;
          *(float4*)&Out[(size_t)gr * 128 + colv] = *(const float4*)&epf[row * 132 + colv];
        }
      }
    }
  }
}

// ========== aggregations: wave/node, 16-lane x uint4 rows, 8 rows in flight ==========

__global__ __launch_bounds__(256) void k_agg_gcn(const ushort* __restrict__ Hb,
                                                 const int* __restrict__ rowptr,
                                                 const int* __restrict__ col,
                                                 const float* __restrict__ dinv,
                                                 const float* __restrict__ bias,
                                                 ushort* __restrict__ X1b, int N) {
  int wid = (blockIdx.x * 256 + threadIdx.x) >> 6;
  int l = threadIdx.x & 63;
  if (wid >= N) return;
  int q = l >> 4, lc = l & 15;
  float di = dinv[wid];
  float acc[8] = {0.f, 0.f, 0.f, 0.f, 0.f, 0.f, 0.f, 0.f};
  int s0 = rowptr[wid], s1 = rowptr[wid + 1];
  for (int j0 = s0; j0 < s1; j0 += 64) {
    int rem = s1 - j0;
    int idx = 0;
    float dv = 0.f;
    if (l < rem) {
      idx = col[j0 + l];
      dv = dinv[idx];
    }
    int m = rem < 64 ? rem : 64;
    for (int jj = 0; jj < m; jj += 8) {
      int ra = jj + q, rb = jj + 4 + q;
      int sa = __shfl(idx, ra); float da = __shfl(dv, ra);
      int sb = __shfl(idx, rb); float db = __shfl(dv, rb);  // rows >= rem carry d=0
      uint4 va = *(const uint4*)&Hb[(size_t)sa * 128 + lc * 8];
      uint4 vb = *(const uint4*)&Hb[(size_t)sb * 128 + lc * 8];
      acc[0] = fmaf(b2f_lo(va.x), da, acc[0]); acc[1] = fmaf(b2f_hi(va.x), da, acc[1]);
      acc[2] = fmaf(b2f_lo(va.y), da, acc[2]); acc[3] = fmaf(b2f_hi(va.y), da, acc[3]);
      acc[4] = fmaf(b2f_lo(va.z), da, acc[4]); acc[5] = fmaf(b2f_hi(va.z), da, acc[5]);
      acc[6] = fmaf(b2f_lo(va.w), da, acc[6]); acc[7] = fmaf(b2f_hi(va.w), da, acc[7]);
      acc[0] = fmaf(b2f_lo(vb.x), db, acc[0]); acc[1] = fmaf(b2f_hi(vb.x), db, acc[1]);
      acc[2] = fmaf(b2f_lo(vb.y), db, acc[2]); acc[3] = fmaf(b2f_hi(vb.y), db, acc[3]);
      acc[4] = fmaf(b2f_lo(vb.z), db, acc[4]); acc[5] = fmaf(b2f_hi(vb.z), db, acc[5]);
      acc[6] = fmaf(b2f_lo(vb.w), db, acc[6]); acc[7] = fmaf(b2f_hi(vb.w), db, acc[7]);
    }
  }
#pragma unroll
  for (int k = 0; k < 8; ++k) {
    acc[k] += __shfl_xor(acc[k], 16);
    acc[k] += __shfl_xor(acc[k], 32);
  }
  if (q == 0) {
    uint4 hv = *(const uint4*)&Hb[(size_t)wid * 128 + lc * 8];
    float4 b0 = *(const float4*)&bias[lc * 8];
    float4 b1 = *(const float4*)&bias[lc * 8 + 4];
    float hvf[8] = {b2f_lo(hv.x), b2f_hi(hv.x), b2f_lo(hv.y), b2f_hi(hv.y),
                    b2f_lo(hv.z), b2f_hi(hv.z), b2f_lo(hv.w), b2f_hi(hv.w)};
    float bb[8] = {b0.x, b0.y, b0.z, b0.w, b1.x, b1.y, b1.z, b1.w};
    u16x8 r;
#pragma unroll
    for (int k = 0; k < 8; ++k) {
      float o = (acc[k] + hvf[k] * di) * di + bb[k];
      r[k] = f2b(fmaxf(o, 0.f));
    }
    *(u16x8*)&X1b[(size_t)wid * 128 + lc * 8] = r;
  }
}

__global__ __launch_bounds__(256) void k_agg_mean(const ushort* __restrict__ Xb,
                                                  const int* __restrict__ rowptr,
                                                  const int* __restrict__ col,
                                                  ushort* __restrict__ Mb, int N) {
  int wid = (blockIdx.x * 256 + threadIdx.x) >> 6;
  int l = threadIdx.x & 63;
  if (wid >= N) return;
  int q = l >> 4, lc = l & 15;
  float acc[8] = {0.f, 0.f, 0.f, 0.f, 0.f, 0.f, 0.f, 0.f};
  int s0 = rowptr[wid], s1 = rowptr[wid + 1];
  for (int j0 = s0; j0 < s1; j0 += 64) {
    int rem = s1 - j0;
    int idx = 0;
    float w = 0.f;
    if (l < rem) {
      idx = col[j0 + l];
      w = 1.f;
    }
    int m = rem < 64 ? rem : 64;
    for (int jj = 0; jj < m; jj += 8) {
      int ra = jj + q, rb = jj + 4 + q;
      int sa = __shfl(idx, ra); float da = __shfl(w, ra);
      int sb = __shfl(idx, rb); float db = __shfl(w, rb);
      uint4 va = *(const uint4*)&Xb[(size_t)sa * 128 + lc * 8];
      uint4 vb = *(const uint4*)&Xb[(size_t)sb * 128 + lc * 8];
      acc[0] = fmaf(b2f_lo(va.x), da, acc[0]); acc[1] = fmaf(b2f_hi(va.x), da, acc[1]);
      acc[2] = fmaf(b2f_lo(va.y), da, acc[2]); acc[3] = fmaf(b2f_hi(va.y), da, acc[3]);
      acc[4] = fmaf(b2f_lo(va.z), da, acc[4]); acc[5] = fmaf(b2f_hi(va.z), da, acc[5]);
      acc[6] = fmaf(b2f_lo(va.w), da, acc[6]); acc[7] = fmaf(b2f_hi(va.w), da, acc[7]);
      acc[0] = fmaf(b2f_lo(vb.x), db, acc[0]); acc[1] = fmaf(b2f_hi(vb.x), db, acc[1]);
      acc[2] = fmaf(b2f_lo(vb.y), db, acc[2]); acc[3] = fmaf(b2f_hi(vb.y), db, acc[3]);
      acc[4] = fmaf(b2f_lo(vb.z), db, acc[4]); acc[5] = fmaf(b2f_hi(vb.z), db, acc[5]);
      acc[6] = fmaf(b2f_lo(vb.w), db, acc[6]); acc[7] = fmaf(b2f_hi(vb.w), db, acc[7]);
    }
  }
#pragma unroll
  for (int k = 0; k < 8; ++k) {
    acc[k] += __shfl_xor(acc[k], 16);
    acc[k] += __shfl_xor(acc[k], 32);
  }
  if (q == 0) {
    int deg = s1 - s0;
    float inv = 1.f / (float)(deg > 0 ? deg : 1);
    u16x8 r;
#pragma unroll
    for (int k = 0; k < 8; ++k) r[k] = f2b(acc[k] * inv);
    *(u16x8*)&Mb[(size_t)wid * 128 + lc * 8] = r;
  }
}

// ================= launch =================

extern "C" void kernel_launch(void* const* d_in, const int* in_sizes, int n_in,
                              void* d_out, int out_size, void* d_ws, size_t ws_size,
                              hipStream_t stream) {
  const float* feat = (const float*)d_in[0];
  const int* ei     = (const int*)d_in[1];
  const float* W1   = (const float*)d_in[2];
  const float* b1   = (const float*)d_in[3];
  const float* Wl   = (const float*)d_in[4];
  const float* bl   = (const float*)d_in[5];
  const float* Wr   = (const float*)d_in[6];
  float* out = (float*)d_out;

  int N = in_sizes[0] / 128;
  int E = in_sizes[1] / 2;

  char* ws = (char*)d_ws;
  size_t off = 0;
  auto alloc = [&](size_t bytes) {
    void* p = ws + off;
    off += (bytes + 255) & ~(size_t)255;
    return p;
  };
  ushort* Hb    = (ushort*)alloc((size_t)N * 128 * 2);  // h bf16; reused as mean
  ushort* X1b   = (ushort*)alloc((size_t)N * 128 * 2);  // layer-1 output bf16
  int*   rowptr = (int*)alloc((size_t)(N + 1) * 4);
  float* dinv   = (float*)alloc((size_t)N * 4);
  int*   col    = (int*)alloc((size_t)E * 4);
  int*   bhist  = (int*)alloc(1024);
  int*   bbase  = (int*)alloc(1024);
  int*   bcursor= (int*)alloc(1024);
  // keyval pairs alias Hb: dead before k_gemm1 writes Hb
  uint2* keyval = (uint2*)Hb;

  int NB = (N + 1023) >> 10;          // buckets of 1024 nodes (<=256)
  int NBLK = (E + 16383) / 16384;     // edge chunks

  hipMemsetAsync(bhist, 0, 1024, stream);
  k_bhist<<<NBLK, 256, 0, stream>>>(ei + E, bhist, E);
  k_bscan<<<1, 256, 0, stream>>>(bhist, bbase, bcursor, rowptr, NB, N, E);
  k_scatter<<<NBLK, 256, 0, stream>>>(ei, bcursor, keyval, E);
  k_build<<<NB, 1024, 0, stream>>>(keyval, bbase, bhist, rowptr, dinv, col, N);

  int gb = (N + 127) / 128;
  k_gemm1<<<gb, 256, 0, stream>>>(feat, W1, Hb, N);
  k_agg_gcn<<<(N + 3) / 4, 256, 0, stream>>>(Hb, rowptr, col, dinv, b1, X1b, N);
  k_agg_mean<<<(N + 3) / 4, 256, 0, stream>>>(X1b, rowptr, col, Hb, N);
  k_gemm2<<<gb, 256, 0, stream>>>(Hb, X1b, Wl, Wr, bl, out, N);
}